// Round 10
// baseline (226.024 us; speedup 1.0000x reference)
//
#include <hip/hip_runtime.h>

typedef __attribute__((ext_vector_type(8))) short bf16x8;
typedef __attribute__((ext_vector_type(4))) float f32x4;
typedef __attribute__((ext_vector_type(4))) unsigned short u16x4;

#define MFMA16(a, b, c) __builtin_amdgcn_mfma_f32_16x16x32_bf16((a), (b), (c), 0, 0, 0)

static constexpr int D_MODEL = 1024;
static constexpr int SEQ = 2048;
static constexpr int NH = 16;
static constexpr int HD = 64;
static constexpr int LDA = 40;   // slow-path GEMM LDS row stride
static constexpr int PSTR = 68;  // attn P-buffer row stride: 136B (phase-conflict-free)
static constexpr int MST = 136;  // V^T repack LDS row stride (elems)
static constexpr float NEG_BIG = -1.0e30f;

__device__ __forceinline__ unsigned short f2bf(float f) {
  union { float f; unsigned int u; } v; v.f = f;
  unsigned int r = v.u + 0x7fffu + ((v.u >> 16) & 1u);
  return (unsigned short)(r >> 16);
}

// Adaptive 8-element load: bf16 direct, or f32 -> RNE bf16 convert (slow path).
__device__ __forceinline__ bf16x8 ld8(const void* p, size_t eidx, int bf) {
  if (bf) return *(const bf16x8*)((const unsigned short*)p + eidx);
  const float* f = (const float*)p + eidx;
  f32x4 lo = *(const f32x4*)f;
  f32x4 hi = *(const f32x4*)(f + 4);
  bf16x8 r;
  r[0] = (short)f2bf(lo[0]); r[1] = (short)f2bf(lo[1]);
  r[2] = (short)f2bf(lo[2]); r[3] = (short)f2bf(lo[3]);
  r[4] = (short)f2bf(hi[0]); r[5] = (short)f2bf(hi[1]);
  r[6] = (short)f2bf(hi[2]); r[7] = (short)f2bf(hi[3]);
  return r;
}

// async global -> LDS, 16B per lane (dst = wave-uniform base + lane*16)
__device__ __forceinline__ void async16(const unsigned short* g, unsigned short* l) {
  __builtin_amdgcn_global_load_lds(
      (const __attribute__((address_space(1))) void*)g,
      (__attribute__((address_space(3))) void*)l, 16, 0, 0);
}

// ---- dtype detector ----
__global__ __launch_bounds__(64) void detect_kernel(
    const unsigned short* __restrict__ xs, int* __restrict__ flag) {
  int lane = threadIdx.x;
  unsigned short s = xs[2 * lane];
  int e = (s >> 7) & 0xFF;
  bool hit = (e >= 117 && e <= 129);
  unsigned long long m = __ballot(hit);
  if (lane == 0) { flag[0] = (__popcll(m) >= 32) ? 1 : 0; flag[1] = 1; }
}

// ---- pre-convert X and the four W matrices to bf16 (fast path) ----
__global__ __launch_bounds__(256) void convert_kernel(
    const void* __restrict__ X,
    const void* __restrict__ W0, const void* __restrict__ W1,
    const void* __restrict__ W2, const void* __restrict__ W3,
    const int* __restrict__ flag,
    unsigned short* __restrict__ Xb, unsigned short* __restrict__ Wb)
{
  const int bf = *flag;
  const int ty = blockIdx.y;
  const void* src; unsigned short* dst; size_t n;
  if (ty == 0) { src = X; dst = Xb; n = (size_t)2 * SEQ * D_MODEL; }
  else {
    src = (ty == 1) ? W0 : (ty == 2) ? W1 : (ty == 3) ? W2 : W3;
    dst = Wb + (size_t)(ty - 1) * D_MODEL * D_MODEL;
    n = (size_t)D_MODEL * D_MODEL;
  }
  size_t i = ((size_t)blockIdx.x * 256 + threadIdx.x) * 8;
  if (i >= n) return;
  *(bf16x8*)(dst + i) = ld8(src, i, bf);
}

// ======================= FAST PATH bf16 GEMM =======================
// 128x128 tile, BK=64, global_load_lds width-16 staging into [128][64] LDS
// with XOR-chunk swizzle: LDS[r][c] = global[r][c ^ (r&7)].
__device__ __forceinline__ void gemm_fast_core(
    const unsigned short* __restrict__ A, const unsigned short* __restrict__ B,
    int tm, int tn, unsigned short* As, unsigned short* Bs, f32x4 acc[4][4])
{
  const int t = threadIdx.x;
  const int lane = t & 63;
  const int w = t >> 6;
  const int wm = (w >> 1) * 64, wn = (w & 1) * 64;
  const int quad = lane >> 4, l16 = lane & 15;
  const int srow = lane >> 3;                    // 8 rows per async16 instr
  const int scol = ((lane & 7) ^ srow) * 8;      // swizzled global chunk
  const int xa = l16 & 7;                        // read-side swizzle key

#pragma unroll
  for (int mi = 0; mi < 4; ++mi)
#pragma unroll
    for (int ni = 0; ni < 4; ++ni)
      acc[mi][ni] = (f32x4){0.f, 0.f, 0.f, 0.f};

  for (int k0 = 0; k0 < D_MODEL; k0 += 64) {
    __syncthreads();  // previous iteration's fragment reads complete
#pragma unroll
    for (int j = 0; j < 4; ++j) {
      const int row = w * 32 + j * 8;
      async16(A + (size_t)(tm + row + srow) * D_MODEL + k0 + scol, As + row * 64);
      async16(B + (size_t)(tn + row + srow) * D_MODEL + k0 + scol, Bs + row * 64);
    }
    asm volatile("s_waitcnt vmcnt(0)" ::: "memory");
    __syncthreads();
    bf16x8 af[2][4], bfv[2][4];
#pragma unroll
    for (int ks = 0; ks < 2; ++ks) {
#pragma unroll
      for (int mi = 0; mi < 4; ++mi)
        af[ks][mi] = *(const bf16x8*)(As + (wm + mi * 16 + l16) * 64 +
                                      ((ks * 4 + quad) ^ xa) * 8);
#pragma unroll
      for (int ni = 0; ni < 4; ++ni)
        bfv[ks][ni] = *(const bf16x8*)(Bs + (wn + ni * 16 + l16) * 64 +
                                       ((ks * 4 + quad) ^ xa) * 8);
    }
#pragma unroll
    for (int ks = 0; ks < 2; ++ks)
#pragma unroll
      for (int mi = 0; mi < 4; ++mi)
#pragma unroll
        for (int ni = 0; ni < 4; ++ni)
          acc[mi][ni] = MFMA16(af[ks][mi], bfv[ks][ni], acc[mi][ni]);
  }
}

// QKV fast: 1D grid 768, XCD-partitioned decode for L2 locality.
__global__ __launch_bounds__(256) void qkv_fast_kernel(
    const unsigned short* __restrict__ X,
    const unsigned short* __restrict__ Wb,   // [3][1024][1024] bf16 (q,k,v)
    unsigned short* __restrict__ qd,
    unsigned short* __restrict__ kws,
    unsigned short* __restrict__ vws)
{
  __shared__ __align__(16) unsigned short smem[2 * 128 * 64];
  unsigned short* As = smem;
  unsigned short* Bs = smem + 128 * 64;
  const int bid = blockIdx.x;
  const int xcd = bid & 7, s0 = bid >> 3;
  const int tmg = xcd >> 2, tng = xcd & 3;
  const int tm_local = s0 / 6, zt = s0 % 6;
  const int z = zt >> 1, tn_local = zt & 1;
  const int tm = (tmg * 16 + tm_local) * 128;
  const int tn = (tng * 2 + tn_local) * 128;
  const unsigned short* W = Wb + (size_t)z * D_MODEL * D_MODEL;
  f32x4 acc[4][4];
  gemm_fast_core(X, W, tm, tn, As, Bs, acc);

  const int t = threadIdx.x;
  const int lane = t & 63, w = t >> 6;
  const int wm = (w >> 1) * 64, wn = (w & 1) * 64;
  const int quad = lane >> 4, l16 = lane & 15;

  if (z == 2) {
    // V^T epilogue: LDS transpose repack (2 n-half passes) + coalesced stores.
    const int b = tm >> 11;
    const int sb = tm & 2047;
#pragma unroll
    for (int ph = 0; ph < 2; ++ph) {
      __syncthreads();
      if ((w & 1) == ph) {
#pragma unroll
        for (int mi = 0; mi < 4; ++mi)
#pragma unroll
          for (int ni = 0; ni < 4; ++ni)
#pragma unroll
            for (int r = 0; r < 4; ++r) {
              int m_local = wm + mi * 16 + quad * 4 + r;
              int n_sub = ni * 16 + l16;
              smem[n_sub * MST + m_local] = f2bf(acc[mi][ni][r]);
            }
      }
      __syncthreads();
      const int row = t >> 2, c0 = (t & 3) * 32;
      const int n_g = tn + ph * 64 + row;
      const int h = n_g >> 6, d = n_g & 63;
      unsigned short* dst = vws + (((size_t)b * NH + h) * HD + d) * SEQ + sb + c0;
#pragma unroll
      for (int cc = 0; cc < 4; ++cc)
        *(bf16x8*)(dst + cc * 8) = *(const bf16x8*)(smem + row * MST + c0 + cc * 8);
    }
    return;
  }
#pragma unroll
  for (int mi = 0; mi < 4; ++mi)
#pragma unroll
    for (int ni = 0; ni < 4; ++ni)
#pragma unroll
      for (int r = 0; r < 4; ++r) {
        int m = tm + wm + mi * 16 + quad * 4 + r;
        int n = tn + wn + ni * 16 + l16;
        unsigned short bv = f2bf(acc[mi][ni][r]);
        if (z == 0) {
          qd[(size_t)m * D_MODEL + n] = bv;
        } else {
          int b = m >> 11, sg = m & 2047;
          int h = n >> 6, d = n & 63;
          kws[(((size_t)b * NH + h) * SEQ + sg) * HD + d] = bv;
        }
      }
}

// O-proj fast: 1D grid 256, same XCD partition (tn fastest within XCD).
__global__ __launch_bounds__(256) void oproj_fast_kernel(
    const unsigned short* __restrict__ AW,
    const unsigned short* __restrict__ Wo,
    float* __restrict__ tmp)
{
  __shared__ __align__(16) unsigned short As[128 * 64];
  __shared__ __align__(16) unsigned short Bs[128 * 64];
  const int bid = blockIdx.x;
  const int xcd = bid & 7, s0 = bid >> 3;
  const int tmg = xcd >> 2, tng = xcd & 3;
  const int tm = (tmg * 16 + (s0 >> 1)) * 128;
  const int tn = (tng * 2 + (s0 & 1)) * 128;
  f32x4 acc[4][4];
  gemm_fast_core(AW, Wo, tm, tn, As, Bs, acc);

  const int t = threadIdx.x;
  const int lane = t & 63, w = t >> 6;
  const int wm = (w >> 1) * 64, wn = (w & 1) * 64;
  const int quad = lane >> 4, l16 = lane & 15;
#pragma unroll
  for (int mi = 0; mi < 4; ++mi)
#pragma unroll
    for (int ni = 0; ni < 4; ++ni)
#pragma unroll
      for (int r = 0; r < 4; ++r) {
        int m = tm + wm + mi * 16 + quad * 4 + r;
        int n = tn + wn + ni * 16 + l16;
        tmp[(size_t)m * D_MODEL + n] = acc[mi][ni][r];
      }
}

// ======================= SLOW PATH GEMM (dtype-adaptive) =======================
__device__ __forceinline__ void gemm_tile_128x128(
    const void* __restrict__ A, const void* __restrict__ B, int bf,
    int tm, int tn, unsigned short* As, unsigned short* Bs, f32x4 acc[4][4])
{
  const int t = threadIdx.x;
  const int lane = t & 63;
  const int w = t >> 6;
  const int wm = (w >> 1) * 64, wn = (w & 1) * 64;
  const int quad = lane >> 4, l16 = lane & 15;
  const int r0 = t >> 2, kc = (t & 3) * 8;
  const int r1 = r0 + 64;

#pragma unroll
  for (int mi = 0; mi < 4; ++mi)
#pragma unroll
    for (int ni = 0; ni < 4; ++ni)
      acc[mi][ni] = (f32x4){0.f, 0.f, 0.f, 0.f};

  for (int k0 = 0; k0 < D_MODEL; k0 += 32) {
    bf16x8 a0 = ld8(A, (size_t)(tm + r0) * D_MODEL + k0 + kc, bf);
    bf16x8 a1 = ld8(A, (size_t)(tm + r1) * D_MODEL + k0 + kc, bf);
    bf16x8 b0 = ld8(B, (size_t)(tn + r0) * D_MODEL + k0 + kc, bf);
    bf16x8 b1 = ld8(B, (size_t)(tn + r1) * D_MODEL + k0 + kc, bf);
    __syncthreads();
    *(bf16x8*)(As + r0 * LDA + kc) = a0;
    *(bf16x8*)(As + r1 * LDA + kc) = a1;
    *(bf16x8*)(Bs + r0 * LDA + kc) = b0;
    *(bf16x8*)(Bs + r1 * LDA + kc) = b1;
    __syncthreads();
    bf16x8 af[4], bfv[4];
#pragma unroll
    for (int mi = 0; mi < 4; ++mi)
      af[mi] = *(const bf16x8*)(As + (wm + mi * 16 + l16) * LDA + quad * 8);
#pragma unroll
    for (int ni = 0; ni < 4; ++ni)
      bfv[ni] = *(const bf16x8*)(Bs + (wn + ni * 16 + l16) * LDA + quad * 8);
#pragma unroll
    for (int mi = 0; mi < 4; ++mi)
#pragma unroll
      for (int ni = 0; ni < 4; ++ni)
        acc[mi][ni] = MFMA16(af[mi], bfv[ni], acc[mi][ni]);
  }
}

__global__ __launch_bounds__(256) void qkv_kernel(
    const void* __restrict__ X,
    const void* __restrict__ Wq,
    const void* __restrict__ Wk,
    const void* __restrict__ Wv,
    const int* __restrict__ flag,
    unsigned short* __restrict__ qd,
    unsigned short* __restrict__ kws,
    unsigned short* __restrict__ vws)
{
  __shared__ __align__(16) unsigned short As[128 * LDA];
  __shared__ __align__(16) unsigned short Bs[128 * LDA];
  const int bf = *flag;
  const int z = blockIdx.z;
  const void* W = (z == 0) ? Wq : ((z == 1) ? Wk : Wv);
  const int tm = blockIdx.y * 128, tn = blockIdx.x * 128;
  f32x4 acc[4][4];
  gemm_tile_128x128(X, W, bf, tm, tn, As, Bs, acc);

  const int t = threadIdx.x;
  const int lane = t & 63, w = t >> 6;
  const int wm = (w >> 1) * 64, wn = (w & 1) * 64;
  const int quad = lane >> 4, l16 = lane & 15;
#pragma unroll
  for (int mi = 0; mi < 4; ++mi)
#pragma unroll
    for (int ni = 0; ni < 4; ++ni)
#pragma unroll
      for (int r = 0; r < 4; ++r) {
        int m = tm + wm + mi * 16 + quad * 4 + r;
        int n = tn + wn + ni * 16 + l16;
        unsigned short bv = f2bf(acc[mi][ni][r]);
        if (z == 0) {
          qd[(size_t)m * D_MODEL + n] = bv;
        } else {
          int b = m >> 11, s = m & 2047;
          int h = n >> 6, d = n & 63;
          if (z == 1) kws[(((size_t)b * NH + h) * SEQ + s) * HD + d] = bv;
          else        vws[(((size_t)b * NH + h) * HD + d) * SEQ + s] = bv;
        }
      }
}

__global__ __launch_bounds__(256) void oproj_kernel(
    const unsigned short* __restrict__ AW,
    const void* __restrict__ Wo,
    const int* __restrict__ flag,
    float* __restrict__ tmp)
{
  __shared__ __align__(16) unsigned short As[128 * LDA];
  __shared__ __align__(16) unsigned short Bs[128 * LDA];
  const int bf = *flag;
  const int t = threadIdx.x;
  const int lane = t & 63;
  const int w = t >> 6;
  const int wm = (w >> 1) * 64, wn = (w & 1) * 64;
  const int quad = lane >> 4, l16 = lane & 15;
  const int r0 = t >> 2, kc = (t & 3) * 8;
  const int r1 = r0 + 64;
  const int tm = blockIdx.y * 128, tn = blockIdx.x * 128;
  f32x4 acc[4][4];
#pragma unroll
  for (int mi = 0; mi < 4; ++mi)
#pragma unroll
    for (int ni = 0; ni < 4; ++ni)
      acc[mi][ni] = (f32x4){0.f, 0.f, 0.f, 0.f};

  for (int k0 = 0; k0 < D_MODEL; k0 += 32) {
    bf16x8 a0 = *(const bf16x8*)(AW + (size_t)(tm + r0) * D_MODEL + k0 + kc);
    bf16x8 a1 = *(const bf16x8*)(AW + (size_t)(tm + r1) * D_MODEL + k0 + kc);
    bf16x8 b0 = ld8(Wo, (size_t)(tn + r0) * D_MODEL + k0 + kc, bf);
    bf16x8 b1 = ld8(Wo, (size_t)(tn + r1) * D_MODEL + k0 + kc, bf);
    __syncthreads();
    *(bf16x8*)(As + r0 * LDA + kc) = a0;
    *(bf16x8*)(As + r1 * LDA + kc) = a1;
    *(bf16x8*)(Bs + r0 * LDA + kc) = b0;
    *(bf16x8*)(Bs + r1 * LDA + kc) = b1;
    __syncthreads();
    bf16x8 af[4], bfv[4];
#pragma unroll
    for (int mi = 0; mi < 4; ++mi)
      af[mi] = *(const bf16x8*)(As + (wm + mi * 16 + l16) * LDA + quad * 8);
#pragma unroll
    for (int ni = 0; ni < 4; ++ni)
      bfv[ni] = *(const bf16x8*)(Bs + (wn + ni * 16 + l16) * LDA + quad * 8);
#pragma unroll
    for (int mi = 0; mi < 4; ++mi)
#pragma unroll
      for (int ni = 0; ni < 4; ++ni)
        acc[mi][ni] = MFMA16(af[mi], bfv[ni], acc[mi][ni]);
  }
#pragma unroll
  for (int mi = 0; mi < 4; ++mi)
#pragma unroll
    for (int ni = 0; ni < 4; ++ni)
#pragma unroll
      for (int r = 0; r < 4; ++r) {
        int m = tm + wm + mi * 16 + quad * 4 + r;
        int n = tn + wn + ni * 16 + l16;
        tmp[(size_t)m * D_MODEL + n] = acc[mi][ni][r];
      }
}

// ======================= Flash attention (block-staged KV, no-max softmax) =======
// 512 blocks = 32 (b,h) x 16 q-groups of 128 rows. Wave owns 32 rows (2 strips).
// Softmax computed WITHOUT running max (shift-invariant; scores bounded, fp32
// range sufficient) -> no cross-lane chain inside the kt loop.
// K/V^T staged once per block per kt (double-buffered, XOR-swizzled).
// Longest blocks dispatched first (g descending).
__global__ __launch_bounds__(256) void attn_kernel(
    unsigned short* __restrict__ Qd,   // Q in (plain [m,n]), attn-out in place
    const unsigned short* __restrict__ Kb,
    const unsigned short* __restrict__ Vt,
    const int* __restrict__ causal_p)
{
  __shared__ __align__(16) unsigned short Ks[2][64 * 64];
  __shared__ __align__(16) unsigned short Vs[2][64 * 64];
  __shared__ __align__(16) unsigned short pbuf[4 * 16 * PSTR];
  const int bid = blockIdx.x;
  const int xcd = bid & 7, slot = bid >> 3;     // 512 blocks -> 64 slots/xcd
  const int bh = xcd * 4 + (slot >> 4);
  const int g = 15 - (slot & 15);               // 128-row q group, longest first
  const int b = bh >> 4, h = bh & 15;
  const int t = threadIdx.x, lane = t & 63, w = t >> 6;
  const int quad = lane >> 4, l16 = lane & 15;
  const int causal = *causal_p;
  unsigned short* qh = Qd + (size_t)b * SEQ * D_MODEL + h * HD;  // row stride D_MODEL
  const unsigned short* kh = Kb + ((size_t)b * NH + h) * SEQ * HD;
  const unsigned short* vh = Vt + ((size_t)b * NH + h) * HD * SEQ;
  unsigned short* pw = pbuf + w * 16 * PSTR;
  const float Cs = 0.125f * 1.4426950408889634f;  // scale * log2(e)
  const int srow = lane >> 3;                     // staging: 8 rows / instr
  const int gcol = ((lane & 7) ^ srow) * 8;       // swizzled global chunk
  const int xa = l16 & 7;                         // read-side swizzle key
  const int dtile = 2 * g + (w >> 1);             // this wave's diagonal kv tile
  const int ktend = causal ? (2 * g + 2) : (SEQ / 64);

  // Q fragments for the wave's two 16-row strips
  int q0[2];
  bf16x8 aq[2][2];
#pragma unroll
  for (int s = 0; s < 2; ++s) {
    q0[s] = g * 128 + w * 32 + s * 16;
#pragma unroll
    for (int ch = 0; ch < 2; ++ch)
      aq[s][ch] = *(const bf16x8*)(qh + (size_t)(q0[s] + l16) * D_MODEL +
                                   ch * 32 + quad * 8);
  }

  f32x4 oaccT[2][4];
#pragma unroll
  for (int s = 0; s < 2; ++s)
#pragma unroll
    for (int db = 0; db < 4; ++db) oaccT[s][db] = (f32x4){0.f, 0.f, 0.f, 0.f};
  float lsum[2] = {0.f, 0.f};

  // prologue: stage tile 0 into buffer 0
#pragma unroll
  for (int j2 = 0; j2 < 2; ++j2) {
    const int row = w * 16 + j2 * 8;
    async16(kh + (size_t)(row + srow) * HD + gcol, &Ks[0][row * 64]);
    async16(vh + (size_t)(row + srow) * SEQ + gcol, &Vs[0][row * 64]);
  }

  for (int kt = 0; kt < ktend; ++kt) {
    const int cur = kt & 1;
    asm volatile("s_waitcnt vmcnt(0)" ::: "memory");
    __syncthreads();                 // tile kt fully staged by all waves
    if (kt + 1 < ktend) {            // stage kt+1 into the other buffer
      const int nxt = cur ^ 1;
#pragma unroll
      for (int j2 = 0; j2 < 2; ++j2) {
        const int row = w * 16 + j2 * 8;
        async16(kh + (size_t)((kt + 1) * 64 + row + srow) * HD + gcol,
                &Ks[nxt][row * 64]);
        async16(vh + (size_t)(row + srow) * SEQ + (kt + 1) * 64 + gcol,
                &Vs[nxt][row * 64]);
      }
    }
    if (causal && kt > dtile) continue;  // fully-masked tile for this wave

    // fragments from LDS (shared by both strips)
    bf16x8 kfr[4][2], vfr[4][2];
#pragma unroll
    for (int cb = 0; cb < 4; ++cb)
#pragma unroll
      for (int hf = 0; hf < 2; ++hf) {
        kfr[cb][hf] = *(const bf16x8*)(&Ks[cur][(cb * 16 + l16) * 64 +
                                                ((hf * 4 + quad) ^ xa) * 8]);
        vfr[cb][hf] = *(const bf16x8*)(&Vs[cur][(cb * 16 + l16) * 64 +
                                                ((hf * 4 + quad) ^ xa) * 8]);
      }
#pragma unroll
    for (int s = 0; s < 2; ++s) {
      // S^T = K·Q^T : C col = q (l16), row = kv (quad*4+r)
      f32x4 sc[4];
#pragma unroll
      for (int cb = 0; cb < 4; ++cb) {
        sc[cb] = (f32x4){0.f, 0.f, 0.f, 0.f};
        sc[cb] = MFMA16(kfr[cb][0], aq[s][0], sc[cb]);
        sc[cb] = MFMA16(kfr[cb][1], aq[s][1], sc[cb]);
      }
      if (causal && kt == dtile) {
        int q = q0[s] + l16;
#pragma unroll
        for (int cb = 0; cb < 4; ++cb)
#pragma unroll
          for (int r = 0; r < 4; ++r)
            if (kt * 64 + cb * 16 + quad * 4 + r > q) sc[cb][r] = NEG_BIG;
      }
      // no-max softmax: p = exp2(s*Cs); masked -> exp2(-huge) = 0
      float ls = 0.f;
#pragma unroll
      for (int cb = 0; cb < 4; ++cb) {
        u16x4 pk;
#pragma unroll
        for (int r = 0; r < 4; ++r) {
          float p = __builtin_amdgcn_exp2f(sc[cb][r] * Cs);
          ls += p;
          pk[r] = f2bf(p);
        }
        *(u16x4*)(pw + l16 * PSTR + cb * 16 + quad * 4) = pk;  // C-layout -> LDS
      }
      lsum[s] += ls;
      asm volatile("s_waitcnt lgkmcnt(0)" ::: "memory");  // P writes done (per-wave)
      bf16x8 bp[2];
#pragma unroll
      for (int hf = 0; hf < 2; ++hf) {
        u16x4 plo = *(const u16x4*)(pw + l16 * PSTR + hf * 32 + quad * 8);
        u16x4 phi = *(const u16x4*)(pw + l16 * PSTR + hf * 32 + quad * 8 + 4);
        bf16x8 bb;
        bb[0] = (short)plo[0]; bb[1] = (short)plo[1];
        bb[2] = (short)plo[2]; bb[3] = (short)plo[3];
        bb[4] = (short)phi[0]; bb[5] = (short)phi[1];
        bb[6] = (short)phi[2]; bb[7] = (short)phi[3];
        bp[hf] = bb;
      }
      // O^T += V^T · P^T : C col = q, row = d
#pragma unroll
      for (int db = 0; db < 4; ++db) {
        oaccT[s][db] = MFMA16(vfr[db][0], bp[0], oaccT[s][db]);
        oaccT[s][db] = MFMA16(vfr[db][1], bp[1], oaccT[s][db]);
      }
    }
  }
  // epilogue per strip: reduce lsum over quads, write packed bf16 in place
#pragma unroll
  for (int s = 0; s < 2; ++s) {
    float l = lsum[s];
    l += __shfl_xor(l, 16, 64);
    l += __shfl_xor(l, 32, 64);
    float inv = 1.0f / l;
#pragma unroll
    for (int db = 0; db < 4; ++db) {
      u16x4 o;
#pragma unroll
      for (int r = 0; r < 4; ++r) o[r] = f2bf(oaccT[s][db][r] * inv);
      *(u16x4*)(qh + (size_t)(q0[s] + l16) * D_MODEL + db * 16 + quad * 4) = o;
    }
  }
}

// ---- final: d_out <- tmp, dtype per detected flag ----
__global__ __launch_bounds__(256) void final_kernel(
    const float* __restrict__ tmp, void* __restrict__ out,
    const int* __restrict__ flag)
{
  const int bf = *flag;
  size_t i = ((size_t)blockIdx.x * 256 + threadIdx.x) * 8;
  f32x4 lo = *(const f32x4*)(tmp + i);
  f32x4 hi = *(const f32x4*)(tmp + i + 4);
  if (bf) {
    bf16x8 r;
    r[0] = (short)f2bf(lo[0]); r[1] = (short)f2bf(lo[1]);
    r[2] = (short)f2bf(lo[2]); r[3] = (short)f2bf(lo[3]);
    r[4] = (short)f2bf(hi[0]); r[5] = (short)f2bf(hi[1]);
    r[6] = (short)f2bf(hi[2]); r[7] = (short)f2bf(hi[3]);
    *(bf16x8*)((unsigned short*)out + i) = r;
  } else {
    *(f32x4*)((float*)out + i) = lo;
    *(f32x4*)((float*)out + i + 4) = hi;
  }
}

extern "C" void kernel_launch(void* const* d_in, const int* in_sizes, int n_in,
                              void* d_out, int out_size, void* d_ws, size_t ws_size,
                              hipStream_t stream) {
  const void* X  = d_in[0];
  const void* Wq = d_in[1];
  const void* Wk = d_in[2];
  const void* Wv = d_in[3];
  const void* Wo = d_in[4];
  const int* causal = (const int*)d_in[5];

  const size_t NE = (size_t)2 * SEQ * D_MODEL;   // 4,194,304 elems
  const size_t WE = (size_t)D_MODEL * D_MODEL;   // 1,048,576 elems
  int* flag0 = (int*)d_ws;
  int* flag1 = flag0 + 1;
  unsigned short* kws = (unsigned short*)((char*)d_ws + 64);  // K  [b,h,s,d]  8MB
  unsigned short* vws = kws + NE;                             // V^T [b,h,d,s] 8MB
  float* tmp = (float*)kws;                                   // 16MB over dead K+V
  unsigned short* Wb = vws + NE;                              // 4x bf16 W, 8MB
  unsigned short* qd = (unsigned short*)d_out;                // Q bf16, lower 8MB
  unsigned short* Xb = qd + NE;                               // X bf16, upper 8MB (f32 out)

  const bool big = ws_size >= (size_t)64 + 24ull * 1024 * 1024;

  hipLaunchKernelGGL(detect_kernel, dim3(1), dim3(64), 0, stream,
                     (const unsigned short*)X, flag0);
  if (big) {
    hipLaunchKernelGGL(convert_kernel, dim3(2048, 5), dim3(256), 0, stream,
                       X, Wq, Wk, Wv, Wo, flag0, Xb, Wb);
    hipLaunchKernelGGL(qkv_fast_kernel, dim3(768), dim3(256), 0, stream,
                       Xb, Wb, qd, kws, vws);
    hipLaunchKernelGGL(attn_kernel, dim3(512), dim3(256), 0, stream,
                       qd, kws, vws, causal);
    hipLaunchKernelGGL(oproj_fast_kernel, dim3(256), dim3(256), 0, stream,
                       qd, Wb + 3 * WE, tmp);
  } else {
    hipLaunchKernelGGL(qkv_kernel, dim3(8, 32, 3), dim3(256), 0, stream,
                       X, Wq, Wk, Wv, flag0, qd, kws, vws);
    hipLaunchKernelGGL(attn_kernel, dim3(512), dim3(256), 0, stream,
                       qd, kws, vws, causal);
    hipLaunchKernelGGL(oproj_kernel, dim3(8, 32), dim3(256), 0, stream,
                       qd, Wo, flag0, tmp);
  }
  hipLaunchKernelGGL(final_kernel, dim3(2048), dim3(256), 0, stream,
                     tmp, d_out, flag0);
}

// Round 11
// 218.455 us; speedup vs baseline: 1.0346x; 1.0346x over previous
//
#include <hip/hip_runtime.h>

typedef __attribute__((ext_vector_type(8))) short bf16x8;
typedef __attribute__((ext_vector_type(4))) float f32x4;
typedef __attribute__((ext_vector_type(4))) unsigned short u16x4;

#define MFMA16(a, b, c) __builtin_amdgcn_mfma_f32_16x16x32_bf16((a), (b), (c), 0, 0, 0)

static constexpr int D_MODEL = 1024;
static constexpr int SEQ = 2048;
static constexpr int NH = 16;
static constexpr int HD = 64;
static constexpr int LDA = 40;   // slow-path GEMM LDS row stride
static constexpr int PSTR = 68;  // attn P-buffer row stride: 136B (phase-conflict-free)
static constexpr int MST = 136;  // V^T repack LDS row stride (elems)
static constexpr float NEG_BIG = -1.0e30f;

__device__ __forceinline__ unsigned short f2bf(float f) {
  union { float f; unsigned int u; } v; v.f = f;
  unsigned int r = v.u + 0x7fffu + ((v.u >> 16) & 1u);
  return (unsigned short)(r >> 16);
}

// Adaptive 8-element load: bf16 direct, or f32 -> RNE bf16 convert (slow path).
__device__ __forceinline__ bf16x8 ld8(const void* p, size_t eidx, int bf) {
  if (bf) return *(const bf16x8*)((const unsigned short*)p + eidx);
  const float* f = (const float*)p + eidx;
  f32x4 lo = *(const f32x4*)f;
  f32x4 hi = *(const f32x4*)(f + 4);
  bf16x8 r;
  r[0] = (short)f2bf(lo[0]); r[1] = (short)f2bf(lo[1]);
  r[2] = (short)f2bf(lo[2]); r[3] = (short)f2bf(lo[3]);
  r[4] = (short)f2bf(hi[0]); r[5] = (short)f2bf(hi[1]);
  r[6] = (short)f2bf(hi[2]); r[7] = (short)f2bf(hi[3]);
  return r;
}

// async global -> LDS, 16B per lane (dst = wave-uniform base + lane*16)
__device__ __forceinline__ void async16(const unsigned short* g, unsigned short* l) {
  __builtin_amdgcn_global_load_lds(
      (const __attribute__((address_space(1))) void*)g,
      (__attribute__((address_space(3))) void*)l, 16, 0, 0);
}

// ---- dtype detector ----
__global__ __launch_bounds__(64) void detect_kernel(
    const unsigned short* __restrict__ xs, int* __restrict__ flag) {
  int lane = threadIdx.x;
  unsigned short s = xs[2 * lane];
  int e = (s >> 7) & 0xFF;
  bool hit = (e >= 117 && e <= 129);
  unsigned long long m = __ballot(hit);
  if (lane == 0) { flag[0] = (__popcll(m) >= 32) ? 1 : 0; flag[1] = 1; }
}

// ---- pre-convert X and the four W matrices to bf16 (fast path) ----
__global__ __launch_bounds__(256) void convert_kernel(
    const void* __restrict__ X,
    const void* __restrict__ W0, const void* __restrict__ W1,
    const void* __restrict__ W2, const void* __restrict__ W3,
    const int* __restrict__ flag,
    unsigned short* __restrict__ Xb, unsigned short* __restrict__ Wb)
{
  const int bf = *flag;
  const int ty = blockIdx.y;
  const void* src; unsigned short* dst; size_t n;
  if (ty == 0) { src = X; dst = Xb; n = (size_t)2 * SEQ * D_MODEL; }
  else {
    src = (ty == 1) ? W0 : (ty == 2) ? W1 : (ty == 3) ? W2 : W3;
    dst = Wb + (size_t)(ty - 1) * D_MODEL * D_MODEL;
    n = (size_t)D_MODEL * D_MODEL;
  }
  size_t i = ((size_t)blockIdx.x * 256 + threadIdx.x) * 8;
  if (i >= n) return;
  *(bf16x8*)(dst + i) = ld8(src, i, bf);
}

// ======================= FAST PATH bf16 GEMM =======================
// 128x128 tile, BK=64, global_load_lds width-16 staging into [128][64] LDS
// with XOR-chunk swizzle: LDS[r][c] = global[r][c ^ (r&7)].
__device__ __forceinline__ void gemm_fast_core(
    const unsigned short* __restrict__ A, const unsigned short* __restrict__ B,
    int tm, int tn, unsigned short* As, unsigned short* Bs, f32x4 acc[4][4])
{
  const int t = threadIdx.x;
  const int lane = t & 63;
  const int w = t >> 6;
  const int wm = (w >> 1) * 64, wn = (w & 1) * 64;
  const int quad = lane >> 4, l16 = lane & 15;
  const int srow = lane >> 3;                    // 8 rows per async16 instr
  const int scol = ((lane & 7) ^ srow) * 8;      // swizzled global chunk
  const int xa = l16 & 7;                        // read-side swizzle key

#pragma unroll
  for (int mi = 0; mi < 4; ++mi)
#pragma unroll
    for (int ni = 0; ni < 4; ++ni)
      acc[mi][ni] = (f32x4){0.f, 0.f, 0.f, 0.f};

  for (int k0 = 0; k0 < D_MODEL; k0 += 64) {
    __syncthreads();  // previous iteration's fragment reads complete
#pragma unroll
    for (int j = 0; j < 4; ++j) {
      const int row = w * 32 + j * 8;
      async16(A + (size_t)(tm + row + srow) * D_MODEL + k0 + scol, As + row * 64);
      async16(B + (size_t)(tn + row + srow) * D_MODEL + k0 + scol, Bs + row * 64);
    }
    asm volatile("s_waitcnt vmcnt(0)" ::: "memory");
    __syncthreads();
    bf16x8 af[2][4], bfv[2][4];
#pragma unroll
    for (int ks = 0; ks < 2; ++ks) {
#pragma unroll
      for (int mi = 0; mi < 4; ++mi)
        af[ks][mi] = *(const bf16x8*)(As + (wm + mi * 16 + l16) * 64 +
                                      ((ks * 4 + quad) ^ xa) * 8);
#pragma unroll
      for (int ni = 0; ni < 4; ++ni)
        bfv[ks][ni] = *(const bf16x8*)(Bs + (wn + ni * 16 + l16) * 64 +
                                       ((ks * 4 + quad) ^ xa) * 8);
    }
#pragma unroll
    for (int ks = 0; ks < 2; ++ks)
#pragma unroll
      for (int mi = 0; mi < 4; ++mi)
#pragma unroll
        for (int ni = 0; ni < 4; ++ni)
          acc[mi][ni] = MFMA16(af[ks][mi], bfv[ks][ni], acc[mi][ni]);
  }
}

// QKV fast: 1D grid 768, XCD-partitioned decode for L2 locality.
__global__ __launch_bounds__(256) void qkv_fast_kernel(
    const unsigned short* __restrict__ X,
    const unsigned short* __restrict__ Wb,   // [3][1024][1024] bf16 (q,k,v)
    unsigned short* __restrict__ qd,
    unsigned short* __restrict__ kws,
    unsigned short* __restrict__ vws)
{
  __shared__ __align__(16) unsigned short smem[2 * 128 * 64];
  unsigned short* As = smem;
  unsigned short* Bs = smem + 128 * 64;
  const int bid = blockIdx.x;
  const int xcd = bid & 7, s0 = bid >> 3;
  const int tmg = xcd >> 2, tng = xcd & 3;
  const int tm_local = s0 / 6, zt = s0 % 6;
  const int z = zt >> 1, tn_local = zt & 1;
  const int tm = (tmg * 16 + tm_local) * 128;
  const int tn = (tng * 2 + tn_local) * 128;
  const unsigned short* W = Wb + (size_t)z * D_MODEL * D_MODEL;
  f32x4 acc[4][4];
  gemm_fast_core(X, W, tm, tn, As, Bs, acc);

  const int t = threadIdx.x;
  const int lane = t & 63, w = t >> 6;
  const int wm = (w >> 1) * 64, wn = (w & 1) * 64;
  const int quad = lane >> 4, l16 = lane & 15;

  if (z == 2) {
    // V^T epilogue: LDS transpose repack (2 n-half passes) + coalesced stores.
    const int b = tm >> 11;
    const int sb = tm & 2047;
#pragma unroll
    for (int ph = 0; ph < 2; ++ph) {
      __syncthreads();
      if ((w & 1) == ph) {
#pragma unroll
        for (int mi = 0; mi < 4; ++mi)
#pragma unroll
          for (int ni = 0; ni < 4; ++ni)
#pragma unroll
            for (int r = 0; r < 4; ++r) {
              int m_local = wm + mi * 16 + quad * 4 + r;
              int n_sub = ni * 16 + l16;
              smem[n_sub * MST + m_local] = f2bf(acc[mi][ni][r]);
            }
      }
      __syncthreads();
      const int row = t >> 2, c0 = (t & 3) * 32;
      const int n_g = tn + ph * 64 + row;
      const int h = n_g >> 6, d = n_g & 63;
      unsigned short* dst = vws + (((size_t)b * NH + h) * HD + d) * SEQ + sb + c0;
#pragma unroll
      for (int cc = 0; cc < 4; ++cc)
        *(bf16x8*)(dst + cc * 8) = *(const bf16x8*)(smem + row * MST + c0 + cc * 8);
    }
    return;
  }
#pragma unroll
  for (int mi = 0; mi < 4; ++mi)
#pragma unroll
    for (int ni = 0; ni < 4; ++ni)
#pragma unroll
      for (int r = 0; r < 4; ++r) {
        int m = tm + wm + mi * 16 + quad * 4 + r;
        int n = tn + wn + ni * 16 + l16;
        unsigned short bv = f2bf(acc[mi][ni][r]);
        if (z == 0) {
          qd[(size_t)m * D_MODEL + n] = bv;
        } else {
          int b = m >> 11, sg = m & 2047;
          int h = n >> 6, d = n & 63;
          kws[(((size_t)b * NH + h) * SEQ + sg) * HD + d] = bv;
        }
      }
}

// O-proj fast: 1D grid 256, same XCD partition (tn fastest within XCD).
__global__ __launch_bounds__(256) void oproj_fast_kernel(
    const unsigned short* __restrict__ AW,
    const unsigned short* __restrict__ Wo,
    float* __restrict__ tmp)
{
  __shared__ __align__(16) unsigned short As[128 * 64];
  __shared__ __align__(16) unsigned short Bs[128 * 64];
  const int bid = blockIdx.x;
  const int xcd = bid & 7, s0 = bid >> 3;
  const int tmg = xcd >> 2, tng = xcd & 3;
  const int tm = (tmg * 16 + (s0 >> 1)) * 128;
  const int tn = (tng * 2 + (s0 & 1)) * 128;
  f32x4 acc[4][4];
  gemm_fast_core(AW, Wo, tm, tn, As, Bs, acc);

  const int t = threadIdx.x;
  const int lane = t & 63, w = t >> 6;
  const int wm = (w >> 1) * 64, wn = (w & 1) * 64;
  const int quad = lane >> 4, l16 = lane & 15;
#pragma unroll
  for (int mi = 0; mi < 4; ++mi)
#pragma unroll
    for (int ni = 0; ni < 4; ++ni)
#pragma unroll
      for (int r = 0; r < 4; ++r) {
        int m = tm + wm + mi * 16 + quad * 4 + r;
        int n = tn + wn + ni * 16 + l16;
        tmp[(size_t)m * D_MODEL + n] = acc[mi][ni][r];
      }
}

// ======================= SLOW PATH GEMM (dtype-adaptive) =======================
__device__ __forceinline__ void gemm_tile_128x128(
    const void* __restrict__ A, const void* __restrict__ B, int bf,
    int tm, int tn, unsigned short* As, unsigned short* Bs, f32x4 acc[4][4])
{
  const int t = threadIdx.x;
  const int lane = t & 63;
  const int w = t >> 6;
  const int wm = (w >> 1) * 64, wn = (w & 1) * 64;
  const int quad = lane >> 4, l16 = lane & 15;
  const int r0 = t >> 2, kc = (t & 3) * 8;
  const int r1 = r0 + 64;

#pragma unroll
  for (int mi = 0; mi < 4; ++mi)
#pragma unroll
    for (int ni = 0; ni < 4; ++ni)
      acc[mi][ni] = (f32x4){0.f, 0.f, 0.f, 0.f};

  for (int k0 = 0; k0 < D_MODEL; k0 += 32) {
    bf16x8 a0 = ld8(A, (size_t)(tm + r0) * D_MODEL + k0 + kc, bf);
    bf16x8 a1 = ld8(A, (size_t)(tm + r1) * D_MODEL + k0 + kc, bf);
    bf16x8 b0 = ld8(B, (size_t)(tn + r0) * D_MODEL + k0 + kc, bf);
    bf16x8 b1 = ld8(B, (size_t)(tn + r1) * D_MODEL + k0 + kc, bf);
    __syncthreads();
    *(bf16x8*)(As + r0 * LDA + kc) = a0;
    *(bf16x8*)(As + r1 * LDA + kc) = a1;
    *(bf16x8*)(Bs + r0 * LDA + kc) = b0;
    *(bf16x8*)(Bs + r1 * LDA + kc) = b1;
    __syncthreads();
    bf16x8 af[4], bfv[4];
#pragma unroll
    for (int mi = 0; mi < 4; ++mi)
      af[mi] = *(const bf16x8*)(As + (wm + mi * 16 + l16) * LDA + quad * 8);
#pragma unroll
    for (int ni = 0; ni < 4; ++ni)
      bfv[ni] = *(const bf16x8*)(Bs + (wn + ni * 16 + l16) * LDA + quad * 8);
#pragma unroll
    for (int mi = 0; mi < 4; ++mi)
#pragma unroll
      for (int ni = 0; ni < 4; ++ni)
        acc[mi][ni] = MFMA16(af[mi], bfv[ni], acc[mi][ni]);
  }
}

__global__ __launch_bounds__(256) void qkv_kernel(
    const void* __restrict__ X,
    const void* __restrict__ Wq,
    const void* __restrict__ Wk,
    const void* __restrict__ Wv,
    const int* __restrict__ flag,
    unsigned short* __restrict__ qd,
    unsigned short* __restrict__ kws,
    unsigned short* __restrict__ vws)
{
  __shared__ __align__(16) unsigned short As[128 * LDA];
  __shared__ __align__(16) unsigned short Bs[128 * LDA];
  const int bf = *flag;
  const int z = blockIdx.z;
  const void* W = (z == 0) ? Wq : ((z == 1) ? Wk : Wv);
  const int tm = blockIdx.y * 128, tn = blockIdx.x * 128;
  f32x4 acc[4][4];
  gemm_tile_128x128(X, W, bf, tm, tn, As, Bs, acc);

  const int t = threadIdx.x;
  const int lane = t & 63, w = t >> 6;
  const int wm = (w >> 1) * 64, wn = (w & 1) * 64;
  const int quad = lane >> 4, l16 = lane & 15;
#pragma unroll
  for (int mi = 0; mi < 4; ++mi)
#pragma unroll
    for (int ni = 0; ni < 4; ++ni)
#pragma unroll
      for (int r = 0; r < 4; ++r) {
        int m = tm + wm + mi * 16 + quad * 4 + r;
        int n = tn + wn + ni * 16 + l16;
        unsigned short bv = f2bf(acc[mi][ni][r]);
        if (z == 0) {
          qd[(size_t)m * D_MODEL + n] = bv;
        } else {
          int b = m >> 11, s = m & 2047;
          int h = n >> 6, d = n & 63;
          if (z == 1) kws[(((size_t)b * NH + h) * SEQ + s) * HD + d] = bv;
          else        vws[(((size_t)b * NH + h) * HD + d) * SEQ + s] = bv;
        }
      }
}

__global__ __launch_bounds__(256) void oproj_kernel(
    const unsigned short* __restrict__ AW,
    const void* __restrict__ Wo,
    const int* __restrict__ flag,
    float* __restrict__ tmp)
{
  __shared__ __align__(16) unsigned short As[128 * LDA];
  __shared__ __align__(16) unsigned short Bs[128 * LDA];
  const int bf = *flag;
  const int t = threadIdx.x;
  const int lane = t & 63;
  const int w = t >> 6;
  const int wm = (w >> 1) * 64, wn = (w & 1) * 64;
  const int quad = lane >> 4, l16 = lane & 15;
  const int r0 = t >> 2, kc = (t & 3) * 8;
  const int r1 = r0 + 64;
  const int tm = blockIdx.y * 128, tn = blockIdx.x * 128;
  f32x4 acc[4][4];
#pragma unroll
  for (int mi = 0; mi < 4; ++mi)
#pragma unroll
    for (int ni = 0; ni < 4; ++ni)
      acc[mi][ni] = (f32x4){0.f, 0.f, 0.f, 0.f};

  for (int k0 = 0; k0 < D_MODEL; k0 += 32) {
    bf16x8 a0 = *(const bf16x8*)(AW + (size_t)(tm + r0) * D_MODEL + k0 + kc);
    bf16x8 a1 = *(const bf16x8*)(AW + (size_t)(tm + r1) * D_MODEL + k0 + kc);
    bf16x8 b0 = ld8(Wo, (size_t)(tn + r0) * D_MODEL + k0 + kc, bf);
    bf16x8 b1 = ld8(Wo, (size_t)(tn + r1) * D_MODEL + k0 + kc, bf);
    __syncthreads();
    *(bf16x8*)(As + r0 * LDA + kc) = a0;
    *(bf16x8*)(As + r1 * LDA + kc) = a1;
    *(bf16x8*)(Bs + r0 * LDA + kc) = b0;
    *(bf16x8*)(Bs + r1 * LDA + kc) = b1;
    __syncthreads();
    bf16x8 af[4], bfv[4];
#pragma unroll
    for (int mi = 0; mi < 4; ++mi)
      af[mi] = *(const bf16x8*)(As + (wm + mi * 16 + l16) * LDA + quad * 8);
#pragma unroll
    for (int ni = 0; ni < 4; ++ni)
      bfv[ni] = *(const bf16x8*)(Bs + (wn + ni * 16 + l16) * LDA + quad * 8);
#pragma unroll
    for (int mi = 0; mi < 4; ++mi)
#pragma unroll
      for (int ni = 0; ni < 4; ++ni)
        acc[mi][ni] = MFMA16(af[mi], bfv[ni], acc[mi][ni]);
  }
#pragma unroll
  for (int mi = 0; mi < 4; ++mi)
#pragma unroll
    for (int ni = 0; ni < 4; ++ni)
#pragma unroll
      for (int r = 0; r < 4; ++r) {
        int m = tm + wm + mi * 16 + quad * 4 + r;
        int n = tn + wn + ni * 16 + l16;
        tmp[(size_t)m * D_MODEL + n] = acc[mi][ni][r];
      }
}

// ======================= Flash attention (block-staged KV, no-max softmax) =======
// 512 blocks = 32 (b,h) x 16 q-groups of 128 rows. Wave owns 32 rows (2 strips).
// COMPLEMENTARY-g DISPATCH: first 256 bids carry g descending, second 256 carry
// g ascending, so the two blocks co-resident on one CU (bid, bid+256 under
// round-robin) satisfy g_a + g_b = 15 -> uniform 34 kt-iterations per CU
// (was: same-g pairing -> makespan 64 iters, the R10 plateau).
__global__ __launch_bounds__(256) void attn_kernel(
    unsigned short* __restrict__ Qd,   // Q in (plain [m,n]), attn-out in place
    const unsigned short* __restrict__ Kb,
    const unsigned short* __restrict__ Vt,
    const int* __restrict__ causal_p)
{
  __shared__ __align__(16) unsigned short Ks[2][64 * 64];
  __shared__ __align__(16) unsigned short Vs[2][64 * 64];
  __shared__ __align__(16) unsigned short pbuf[4 * 16 * PSTR];
  const int bid = blockIdx.x;
  const int xcd = bid & 7, slot = bid >> 3;     // 512 blocks -> 64 slots/xcd
  const int bh = xcd * 4 + (slot >> 4);
  const int gx = slot & 15;
  const int g = (slot & 32) ? gx : (15 - gx);   // complementary halves
  const int b = bh >> 4, h = bh & 15;
  const int t = threadIdx.x, lane = t & 63, w = t >> 6;
  const int quad = lane >> 4, l16 = lane & 15;
  const int causal = *causal_p;
  unsigned short* qh = Qd + (size_t)b * SEQ * D_MODEL + h * HD;  // row stride D_MODEL
  const unsigned short* kh = Kb + ((size_t)b * NH + h) * SEQ * HD;
  const unsigned short* vh = Vt + ((size_t)b * NH + h) * HD * SEQ;
  unsigned short* pw = pbuf + w * 16 * PSTR;
  const float Cs = 0.125f * 1.4426950408889634f;  // scale * log2(e)
  const int srow = lane >> 3;                     // staging: 8 rows / instr
  const int gcol = ((lane & 7) ^ srow) * 8;       // swizzled global chunk
  const int xa = l16 & 7;                         // read-side swizzle key
  const int dtile = 2 * g + (w >> 1);             // this wave's diagonal kv tile
  const int ktend = causal ? (2 * g + 2) : (SEQ / 64);

  // Q fragments for the wave's two 16-row strips
  int q0[2];
  bf16x8 aq[2][2];
#pragma unroll
  for (int s = 0; s < 2; ++s) {
    q0[s] = g * 128 + w * 32 + s * 16;
#pragma unroll
    for (int ch = 0; ch < 2; ++ch)
      aq[s][ch] = *(const bf16x8*)(qh + (size_t)(q0[s] + l16) * D_MODEL +
                                   ch * 32 + quad * 8);
  }

  f32x4 oaccT[2][4];
#pragma unroll
  for (int s = 0; s < 2; ++s)
#pragma unroll
    for (int db = 0; db < 4; ++db) oaccT[s][db] = (f32x4){0.f, 0.f, 0.f, 0.f};
  float lsum[2] = {0.f, 0.f};

  // prologue: stage tile 0 into buffer 0
#pragma unroll
  for (int j2 = 0; j2 < 2; ++j2) {
    const int row = w * 16 + j2 * 8;
    async16(kh + (size_t)(row + srow) * HD + gcol, &Ks[0][row * 64]);
    async16(vh + (size_t)(row + srow) * SEQ + gcol, &Vs[0][row * 64]);
  }

  for (int kt = 0; kt < ktend; ++kt) {
    const int cur = kt & 1;
    asm volatile("s_waitcnt vmcnt(0)" ::: "memory");
    __syncthreads();                 // tile kt fully staged by all waves
    if (kt + 1 < ktend) {            // stage kt+1 into the other buffer
      const int nxt = cur ^ 1;
#pragma unroll
      for (int j2 = 0; j2 < 2; ++j2) {
        const int row = w * 16 + j2 * 8;
        async16(kh + (size_t)((kt + 1) * 64 + row + srow) * HD + gcol,
                &Ks[nxt][row * 64]);
        async16(vh + (size_t)(row + srow) * SEQ + (kt + 1) * 64 + gcol,
                &Vs[nxt][row * 64]);
      }
    }
    if (causal && kt > dtile) continue;  // fully-masked tile for this wave

    // fragments from LDS (shared by both strips)
    bf16x8 kfr[4][2], vfr[4][2];
#pragma unroll
    for (int cb = 0; cb < 4; ++cb)
#pragma unroll
      for (int hf = 0; hf < 2; ++hf) {
        kfr[cb][hf] = *(const bf16x8*)(&Ks[cur][(cb * 16 + l16) * 64 +
                                                ((hf * 4 + quad) ^ xa) * 8]);
        vfr[cb][hf] = *(const bf16x8*)(&Vs[cur][(cb * 16 + l16) * 64 +
                                                ((hf * 4 + quad) ^ xa) * 8]);
      }
#pragma unroll
    for (int s = 0; s < 2; ++s) {
      // S^T = K·Q^T : C col = q (l16), row = kv (quad*4+r)
      f32x4 sc[4];
#pragma unroll
      for (int cb = 0; cb < 4; ++cb) {
        sc[cb] = (f32x4){0.f, 0.f, 0.f, 0.f};
        sc[cb] = MFMA16(kfr[cb][0], aq[s][0], sc[cb]);
        sc[cb] = MFMA16(kfr[cb][1], aq[s][1], sc[cb]);
      }
      if (causal && kt == dtile) {
        int q = q0[s] + l16;
#pragma unroll
        for (int cb = 0; cb < 4; ++cb)
#pragma unroll
          for (int r = 0; r < 4; ++r)
            if (kt * 64 + cb * 16 + quad * 4 + r > q) sc[cb][r] = NEG_BIG;
      }
      // no-max softmax: p = exp2(s*Cs); masked -> exp2(-huge) = 0
      float ls = 0.f;
#pragma unroll
      for (int cb = 0; cb < 4; ++cb) {
        u16x4 pk;
#pragma unroll
        for (int r = 0; r < 4; ++r) {
          float p = __builtin_amdgcn_exp2f(sc[cb][r] * Cs);
          ls += p;
          pk[r] = f2bf(p);
        }
        *(u16x4*)(pw + l16 * PSTR + cb * 16 + quad * 4) = pk;  // C-layout -> LDS
      }
      lsum[s] += ls;
      asm volatile("s_waitcnt lgkmcnt(0)" ::: "memory");  // P writes done (per-wave)
      bf16x8 bp[2];
#pragma unroll
      for (int hf = 0; hf < 2; ++hf) {
        u16x4 plo = *(const u16x4*)(pw + l16 * PSTR + hf * 32 + quad * 8);
        u16x4 phi = *(const u16x4*)(pw + l16 * PSTR + hf * 32 + quad * 8 + 4);
        bf16x8 bb;
        bb[0] = (short)plo[0]; bb[1] = (short)plo[1];
        bb[2] = (short)plo[2]; bb[3] = (short)plo[3];
        bb[4] = (short)phi[0]; bb[5] = (short)phi[1];
        bb[6] = (short)phi[2]; bb[7] = (short)phi[3];
        bp[hf] = bb;
      }
      // O^T += V^T · P^T : C col = q, row = d
#pragma unroll
      for (int db = 0; db < 4; ++db) {
        oaccT[s][db] = MFMA16(vfr[db][0], bp[0], oaccT[s][db]);
        oaccT[s][db] = MFMA16(vfr[db][1], bp[1], oaccT[s][db]);
      }
    }
  }
  // epilogue per strip: reduce lsum over quads, write packed bf16 in place
#pragma unroll
  for (int s = 0; s < 2; ++s) {
    float l = lsum[s];
    l += __shfl_xor(l, 16, 64);
    l += __shfl_xor(l, 32, 64);
    float inv = 1.0f / l;
#pragma unroll
    for (int db = 0; db < 4; ++db) {
      u16x4 o;
#pragma unroll
      for (int r = 0; r < 4; ++r) o[r] = f2bf(oaccT[s][db][r] * inv);
      *(u16x4*)(qh + (size_t)(q0[s] + l16) * D_MODEL + db * 16 + quad * 4) = o;
    }
  }
}

// ---- final: d_out <- tmp, dtype per detected flag ----
__global__ __launch_bounds__(256) void final_kernel(
    const float* __restrict__ tmp, void* __restrict__ out,
    const int* __restrict__ flag)
{
  const int bf = *flag;
  size_t i = ((size_t)blockIdx.x * 256 + threadIdx.x) * 8;
  f32x4 lo = *(const f32x4*)(tmp + i);
  f32x4 hi = *(const f32x4*)(tmp + i + 4);
  if (bf) {
    bf16x8 r;
    r[0] = (short)f2bf(lo[0]); r[1] = (short)f2bf(lo[1]);
    r[2] = (short)f2bf(lo[2]); r[3] = (short)f2bf(lo[3]);
    r[4] = (short)f2bf(hi[0]); r[5] = (short)f2bf(hi[1]);
    r[6] = (short)f2bf(hi[2]); r[7] = (short)f2bf(hi[3]);
    *(bf16x8*)((unsigned short*)out + i) = r;
  } else {
    *(f32x4*)((float*)out + i) = lo;
    *(f32x4*)((float*)out + i + 4) = hi;
  }
}

extern "C" void kernel_launch(void* const* d_in, const int* in_sizes, int n_in,
                              void* d_out, int out_size, void* d_ws, size_t ws_size,
                              hipStream_t stream) {
  const void* X  = d_in[0];
  const void* Wq = d_in[1];
  const void* Wk = d_in[2];
  const void* Wv = d_in[3];
  const void* Wo = d_in[4];
  const int* causal = (const int*)d_in[5];

  const size_t NE = (size_t)2 * SEQ * D_MODEL;   // 4,194,304 elems
  const size_t WE = (size_t)D_MODEL * D_MODEL;   // 1,048,576 elems
  int* flag0 = (int*)d_ws;
  int* flag1 = flag0 + 1;
  unsigned short* kws = (unsigned short*)((char*)d_ws + 64);  // K  [b,h,s,d]  8MB
  unsigned short* vws = kws + NE;                             // V^T [b,h,d,s] 8MB
  float* tmp = (float*)kws;                                   // 16MB over dead K+V
  unsigned short* Wb = vws + NE;                              // 4x bf16 W, 8MB
  unsigned short* qd = (unsigned short*)d_out;                // Q bf16, lower 8MB
  unsigned short* Xb = qd + NE;                               // X bf16, upper 8MB (f32 out)

  const bool big = ws_size >= (size_t)64 + 24ull * 1024 * 1024;

  hipLaunchKernelGGL(detect_kernel, dim3(1), dim3(64), 0, stream,
                     (const unsigned short*)X, flag0);
  if (big) {
    hipLaunchKernelGGL(convert_kernel, dim3(2048, 5), dim3(256), 0, stream,
                       X, Wq, Wk, Wv, Wo, flag0, Xb, Wb);
    hipLaunchKernelGGL(qkv_fast_kernel, dim3(768), dim3(256), 0, stream,
                       Xb, Wb, qd, kws, vws);
    hipLaunchKernelGGL(attn_kernel, dim3(512), dim3(256), 0, stream,
                       qd, kws, vws, causal);
    hipLaunchKernelGGL(oproj_fast_kernel, dim3(256), dim3(256), 0, stream,
                       qd, Wb + 3 * WE, tmp);
  } else {
    hipLaunchKernelGGL(qkv_kernel, dim3(8, 32, 3), dim3(256), 0, stream,
                       X, Wq, Wk, Wv, flag0, qd, kws, vws);
    hipLaunchKernelGGL(attn_kernel, dim3(512), dim3(256), 0, stream,
                       qd, kws, vws, causal);
    hipLaunchKernelGGL(oproj_kernel, dim3(8, 32), dim3(256), 0, stream,
                       qd, Wo, flag0, tmp);
  }
  hipLaunchKernelGGL(final_kernel, dim3(2048), dim3(256), 0, stream,
                     tmp, d_out, flag0);
}